// Round 1
// baseline (128.551 us; speedup 1.0000x reference)
//
#include <hip/hip_runtime.h>

// SSIM loss: predict/gt (32,1,512,512) f32, 11-tap separable gaussian (sigma=1.5),
// VALID padding -> 502x502 per image, loss = 1 - mean(ssim_map).

constexpr int WIN = 11;
constexpr int TILE = 32;
constexpr int IN_TILE = TILE + WIN - 1;   // 42
constexpr int H = 512, W = 512, NIMG = 32;
constexpr int OH = H - WIN + 1, OW = W - WIN + 1;  // 502
constexpr int TX = (OW + TILE - 1) / TILE;  // 16
constexpr int TY = (OH + TILE - 1) / TILE;  // 16
constexpr float C1 = 0.009801f;   // (0.01*9.9)^2
constexpr float C2 = 0.088209f;   // (0.03*9.9)^2
constexpr double TOTAL = (double)NIMG * (double)OH * (double)OW;

__global__ void zero_acc_kernel(float* acc) {
    if (threadIdx.x == 0) acc[0] = 0.f;
}

__global__ void finalize_kernel(const float* __restrict__ acc, float* __restrict__ out) {
    if (threadIdx.x == 0) out[0] = 1.f - acc[0];
}

__global__ __launch_bounds__(256) void ssim_main_kernel(const float* __restrict__ P,
                                                        const float* __restrict__ G,
                                                        float* __restrict__ acc) {
    __shared__ float sp[IN_TILE][IN_TILE];        // 42x42 predict tile
    __shared__ float sg[IN_TILE][IN_TILE];        // 42x42 gt tile
    __shared__ float sv[5][TILE][IN_TILE];        // vertically blurred p,g,pp,gg,pg

    const int tid = threadIdx.x;
    const int bid = blockIdx.x;
    const int img = bid / (TX * TY);
    const int t = bid % (TX * TY);
    const int oy0 = (t / TX) * TILE;
    const int ox0 = (t % TX) * TILE;

    const float* p = P + (size_t)img * H * W;
    const float* g = G + (size_t)img * H * W;

    // gaussian weights (normalized), computed per-thread (cheap, exact enough)
    float wgt[WIN];
    {
        float s = 0.f;
#pragma unroll
        for (int i = 0; i < WIN; ++i) {
            float c = (float)(i - WIN / 2);
            wgt[i] = expf(-(c * c) / 4.5f);   // 2*sigma^2 = 4.5
            s += wgt[i];
        }
        float inv = 1.f / s;
#pragma unroll
        for (int i = 0; i < WIN; ++i) wgt[i] *= inv;
    }

    // ---- stage input tiles (clamped at edges; clamped lanes feed only masked outputs)
    for (int idx = tid; idx < IN_TILE * IN_TILE; idx += 256) {
        int r = idx / IN_TILE, c = idx % IN_TILE;
        int gr = min(oy0 + r, H - 1);
        int gc = min(ox0 + c, W - 1);
        sp[r][c] = p[gr * W + gc];
        sg[r][c] = g[gr * W + gc];
    }
    __syncthreads();

    // ---- vertical gaussian pass for 5 quantities
    for (int idx = tid; idx < TILE * IN_TILE; idx += 256) {
        int r = idx / IN_TILE, c = idx % IN_TILE;
        float a0 = 0.f, a1 = 0.f, a2 = 0.f, a3 = 0.f, a4 = 0.f;
#pragma unroll
        for (int k = 0; k < WIN; ++k) {
            float pv = sp[r + k][c];
            float gv = sg[r + k][c];
            float w = wgt[k];
            a0 += w * pv;
            a1 += w * gv;
            a2 += w * (pv * pv);
            a3 += w * (gv * gv);
            a4 += w * (pv * gv);
        }
        sv[0][r][c] = a0;
        sv[1][r][c] = a1;
        sv[2][r][c] = a2;
        sv[3][r][c] = a3;
        sv[4][r][c] = a4;
    }
    __syncthreads();

    // ---- horizontal gaussian pass + SSIM map + local accumulate
    float lsum = 0.f;
    for (int idx = tid; idx < TILE * TILE; idx += 256) {
        int r = idx / TILE, c = idx % TILE;
        if (oy0 + r < OH && ox0 + c < OW) {
            float m1 = 0.f, m2 = 0.f, e11 = 0.f, e22 = 0.f, e12 = 0.f;
#pragma unroll
            for (int k = 0; k < WIN; ++k) {
                float w = wgt[k];
                m1  += w * sv[0][r][c + k];
                m2  += w * sv[1][r][c + k];
                e11 += w * sv[2][r][c + k];
                e22 += w * sv[3][r][c + k];
                e12 += w * sv[4][r][c + k];
            }
            float mu11 = m1 * m1, mu22 = m2 * m2, mu12 = m1 * m2;
            float s11 = e11 - mu11, s22 = e22 - mu22, s12 = e12 - mu12;
            float cs = (2.f * s12 + C2) / (s11 + s22 + C2);
            float ssim = ((2.f * mu12 + C1) / (mu11 + mu22 + C1)) * cs;
            lsum += ssim;
        }
    }

    // ---- block reduction: wave64 shuffle, then cross-wave via LDS
#pragma unroll
    for (int off = 32; off > 0; off >>= 1)
        lsum += __shfl_down(lsum, off, 64);

    __shared__ float wsum[4];
    const int wid = tid >> 6, lane = tid & 63;
    if (lane == 0) wsum[wid] = lsum;
    __syncthreads();
    if (tid == 0) {
        float bs = wsum[0] + wsum[1] + wsum[2] + wsum[3];
        atomicAdd(acc, bs * (float)(1.0 / TOTAL));
    }
}

extern "C" void kernel_launch(void* const* d_in, const int* in_sizes, int n_in,
                              void* d_out, int out_size, void* d_ws, size_t ws_size,
                              hipStream_t stream) {
    const float* P = (const float*)d_in[0];   // predict
    const float* G = (const float*)d_in[1];   // gt
    float* out = (float*)d_out;
    float* acc = (float*)d_ws;

    zero_acc_kernel<<<1, 64, 0, stream>>>(acc);
    ssim_main_kernel<<<NIMG * TX * TY, 256, 0, stream>>>(P, G, acc);
    finalize_kernel<<<1, 64, 0, stream>>>(acc, out);
}